// Round 19
// baseline (222.375 us; speedup 1.0000x reference)
//
#include <hip/hip_runtime.h>
#include <hip/hip_bf16.h>

using bf16 = __hip_bfloat16;
using bf16x8 = __attribute__((ext_vector_type(8))) short;  // 8 bf16 (4 VGPRs)
using f32x4  = __attribute__((ext_vector_type(4))) float;

#define NN 512
#define NS 511

// ---------------- workspace layout (float offsets) ----------------
enum : int {
  WS_FLAG = 0,        // int: 0 = bf16 inputs, 1 = f32 inputs
  WS_X0S  = 16,       // [5][64] species-indexed layer-0 x0 rows
  WS_POS  = 336,      // [512][3] positions fp32 (layer 0)
  WS_POS2 = 1872,     // [512][3] positions after layer-0 update
  WS_DELTA= 3408,     // [512][3] layer-0 displacement
  WS_XS1  = 4960,     // [512][64][4] (x0,x1x,x1y,x1z) for layer 1 — 16B aligned
  WS_A    = 136032,   // [2][512][64][9] partial A sums (sender halves, unscaled)
};                     // end = 725856 floats ~= 2.9 MB

// exact RNE float->bf16 bits (no NaN inputs here)
__device__ __forceinline__ short f2b(float x) {
  unsigned u = __builtin_bit_cast(unsigned, x);
  unsigned r = (u + 0x7fffu + ((u >> 16) & 1u)) >> 16;
  return (short)r;
}

// dtype-branched scalar load (branch, NOT select: f32-view OOB if input is bf16)
__device__ __forceinline__ float ld(const void* p, int i, int isf32) {
  if (isf32) return ((const float*)p)[i];
  return __bfloat162float(((const bf16*)p)[i]);
}

// ---------------- pre (6 blocks): detect + pos convert + X0S ----------------
__global__ __launch_bounds__(256) void k_pre(
    const void* __restrict__ positions, const void* __restrict__ te,
    const void* __restrict__ W_embed, const void* __restrict__ b_embed,
    const void* __restrict__ W_lin, float* __restrict__ ws) {
  const int b = blockIdx.x, t = threadIdx.x;
  __shared__ int flag_s;
  __shared__ float tvp[4][64];
  __shared__ float hst[64];
  __shared__ float xp[4][64];
  if (t < 64) {
    int cnt = 0;
    #pragma unroll
    for (int kq = 0; kq < 4; ++kq) {
      float v = __bfloat162float(((const bf16*)W_embed)[t + kq * 64]);
      float av = fabsf(v);
      cnt += (v == v && av > 1e-8f && av < 1e4f) ? 1 : 0;
    }
    #pragma unroll
    for (int off = 32; off > 0; off >>= 1) cnt += __shfl_down(cnt, off);
    if (t == 0) flag_s = (cnt >= 240) ? 0 : 1;
  }
  __syncthreads();
  const int isf32 = flag_s;

  if (b == 5) {
    if (t == 0) ((int*)ws)[WS_FLAG] = isf32;
    for (int idx = t; idx < NN * 3; idx += 256)
      ws[WS_POS + idx] = ld(positions, idx, isf32);
    return;
  }
  {
    int q = t & 63, kc = t >> 6;
    float ptv = 0.f;
    #pragma unroll
    for (int k = kc * 8; k < kc * 8 + 8; ++k)
      ptv += ld(te, k, isf32) * ld(W_embed, (5 + k) * 64 + q, isf32);
    tvp[kc][q] = ptv;
  }
  __syncthreads();
  if (t < 64)
    hst[t] = tvp[0][t] + tvp[1][t] + tvp[2][t] + tvp[3][t] +
             ld(b_embed, t, isf32) + ld(W_embed, b * 64 + t, isf32);
  __syncthreads();
  {
    int f = t & 63, qc = t >> 6;
    float px = 0.f;
    #pragma unroll
    for (int q2 = qc * 16; q2 < qc * 16 + 16; ++q2)
      px += hst[q2] * ld(W_lin, q2 * 64 + f, isf32);
    xp[qc][f] = px;
  }
  __syncthreads();
  if (t < 64)
    ws[WS_X0S + b * 64 + t] = xp[0][t] + xp[1][t] + xp[2][t] + xp[3][t];
}

// ---------------- edge + aggregate (partial): grid 1024 = j x sender-half ----------
// ft-split across wave pairs (r15 body, arch VGPR ~92, unified ~124 <= 128
// -> 4 waves/SIMD) x sender-halves (r9). Occupancy was GRID-limited at 512
// blocks (~19% = 2048/8192 waves); 1024 blocks at 4 blocks/CU -> ~50%.
// CAPLESS __launch_bounds__ (a min-waves cap causes 50/50 arch/AGPR split
// -> HBM-speed scratch spill; r4-r8/r11). Node tail moved to k_node.
template <int L>
__global__ __launch_bounds__(256) void k_edge(
    const int* __restrict__ nodef, const void* __restrict__ W_e1,
    const void* __restrict__ b_e1, const void* __restrict__ W_e2,
    float* __restrict__ ws) {
  constexpr int HAS1 = L;          // s1==0 in layer 0
  constexpr int K = HAS1 ? 5 : 3;  // s2==0 always
  constexpr int N = K * 64;
  const int j = blockIdx.x & 511;
  const int half = blockIdx.x >> 9;
  const int t = threadIdx.x;
  const int lane = t & 63;
  const int wave = t >> 6;          // 0..3
  const int sh = wave >> 1;         // stile parity within this half
  const int fh = wave & 1;          // f half
  const int quad = lane >> 4;
  const int lo = lane & 15;

  __shared__ short Bhi[N * 40];     // [n][h], row stride 40 shorts (80B)
  __shared__ float red[4][64][9];
  __shared__ float X0l[320];        // L0: species-indexed x0 table

  const int isf32 = ((const int*)ws)[WS_FLAG];

  {  // stage W2 slice -> LDS bf16 (direct bit copy if input already bf16)
    for (int idx = t; idx < N * 32; idx += 256) {
      int n = idx >> 5, h = idx & 31;
      int kp = n >> 6, f = n & 63;
      int src = (L * 32 + h) * 384 + f * 6 + kp;
      short bits;
      if (isf32) bits = f2b(((const float*)W_e2)[src]);
      else       bits = ((const short*)W_e2)[src];
      Bhi[n * 40 + h] = bits;
    }
    if (!HAS1) {
      for (int idx = t; idx < 320; idx += 256) X0l[idx] = ws[WS_X0S + idx];
    }
  }
  const float* pos = ws + (L ? WS_POS2 : WS_POS);
  const f32x4* xs = (const f32x4*)(ws + WS_XS1);  // used only for L==1
  float we1v[8], be1v[8];
  #pragma unroll
  for (int i = 0; i < 8; ++i) {
    we1v[i] = ld(W_e1, L * 32 + quad * 8 + i, isf32);
    be1v[i] = ld(b_e1, L * 32 + quad * 8 + i, isf32);
  }
  const float pjx = pos[j * 3 + 0], pjy = pos[j * 3 + 1], pjz = pos[j * 3 + 2];

  const float s3 = 1.7320508075688772f;
  const float s5h = 1.118033988749895f;    // 0.5*sqrt(5)
  const float s15 = 3.872983346207417f;
  const float s15h = 1.9364916731037085f;  // 0.5*sqrt(15)

  float acc[9][2] = {};  // [c][ftl] — this wave's f-half only
  __syncthreads();

  #pragma unroll 1
  for (int st = sh; st < 16; st += 2) {
    const int stile = half * 16 + st;
    // ---- A fragment: he for sender m=lo, k=quad*8+i ----
    bf16x8 af;
    {
      int ida = stile * 16 + lo;
      int ia = ida + (ida >= j);
      if (ia > 511) ia = 511;
      float pix = pos[ia * 3 + 0], piy = pos[ia * 3 + 1], piz = pos[ia * 3 + 2];
      float vx = pjx - pix, vy = pjy - piy, vz = pjz - piz;
      float r = sqrtf(vx * vx + vy * vy + vz * vz);
      #pragma unroll
      for (int i = 0; i < 8; ++i) {
        float x = r * we1v[i] + be1v[i];
        float he = x / (1.f + __expf(-x));
        af[i] = f2b(he);
      }
    }
    // ---- Y + indices (+ species for L0) for this quad's 4 row-senders ----
    float Y1r[4][3], Y2r[4][5];
    int ir[4], sp4[4];
    bool vld[4];
    #pragma unroll
    for (int r4 = 0; r4 < 4; ++r4) {
      int idx = stile * 16 + quad * 4 + r4;
      vld[r4] = idx < NS;
      int i = idx + (idx >= j);
      if (i > 511) i = 511;
      ir[r4] = i;
      if (!HAS1) sp4[r4] = nodef[i] - 1;
      float pix = pos[i * 3 + 0], piy = pos[i * 3 + 1], piz = pos[i * 3 + 2];
      float vx = pjx - pix, vy = pjy - piy, vz = pjz - piz;
      float r2 = vx * vx + vy * vy + vz * vz;
      float rinv = r2 > 0.f ? rsqrtf(r2) : 0.f;
      float ux = vx * rinv, uy = vy * rinv, uz = vz * rinv;
      Y1r[r4][0] = s3 * ux; Y1r[r4][1] = s3 * uy; Y1r[r4][2] = s3 * uz;
      Y2r[r4][0] = s15 * ux * uy;
      Y2r[r4][1] = s15 * uy * uz;
      Y2r[r4][2] = s5h * (3.f * uz * uz - 1.f);
      Y2r[r4][3] = s15 * ux * uz;
      Y2r[r4][4] = s15h * (ux * ux - uy * uy);
    }
    // ---- this wave's 2 f-subtiles: loads, K MFMAs, message math ----
    #pragma unroll
    for (int ftl = 0; ftl < 2; ++ftl) {
      int ft = fh * 2 + ftl;
      int fcol = ft * 16 + lo;
      f32x4 xv[4];
      if (HAS1) {
        #pragma unroll
        for (int r4 = 0; r4 < 4; ++r4) xv[r4] = xs[ir[r4] * 64 + fcol];
      } else {
        #pragma unroll
        for (int r4 = 0; r4 < 4; ++r4) {
          f32x4 v = {X0l[sp4[r4] * 64 + fcol], 0.f, 0.f, 0.f};
          xv[r4] = v;
        }
      }
      f32x4 C[K];
      #pragma unroll
      for (int kp = 0; kp < K; ++kp) {
        const bf16x8 bh = *(const bf16x8*)&Bhi[(kp * 64 + fcol) * 40 + quad * 8];
        f32x4 c = {0.f, 0.f, 0.f, 0.f};
        C[kp] = __builtin_amdgcn_mfma_f32_16x16x32_bf16(af, bh, c, 0, 0, 0);
      }
      #pragma unroll
      for (int r4 = 0; r4 < 4; ++r4) {
        if (vld[r4]) {
          float s0 = xv[r4].x;
          float w0 = C[0][r4], w1 = C[1][r4], w2 = C[2][r4];
          if (HAS1) {
            float s1x = xv[r4].y, s1y = xv[r4].z, s1z = xv[r4].w;
            float w3 = C[3][r4], w4 = C[4][r4];
            float d1 = s1x * Y1r[r4][0] + s1y * Y1r[r4][1] + s1z * Y1r[r4][2];
            float cx = s1y * Y1r[r4][2] - s1z * Y1r[r4][1];
            float cy = s1z * Y1r[r4][0] - s1x * Y1r[r4][2];
            float cz = s1x * Y1r[r4][1] - s1y * Y1r[r4][0];
            acc[0][ftl] += w0 * s0 + w3 * d1;
            float t1 = w1 * s0;
            acc[1][ftl] += t1 * Y1r[r4][0] + w4 * cx;
            acc[2][ftl] += t1 * Y1r[r4][1] + w4 * cy;
            acc[3][ftl] += t1 * Y1r[r4][2] + w4 * cz;
          } else {
            acc[0][ftl] += w0 * s0;
            float t1 = w1 * s0;
            acc[1][ftl] += t1 * Y1r[r4][0];
            acc[2][ftl] += t1 * Y1r[r4][1];
            acc[3][ftl] += t1 * Y1r[r4][2];
          }
          float t2 = w2 * s0;
          acc[4][ftl] += t2 * Y2r[r4][0];
          acc[5][ftl] += t2 * Y2r[r4][1];
          acc[6][ftl] += t2 * Y2r[r4][2];
          acc[7][ftl] += t2 * Y2r[r4][3];
          acc[8][ftl] += t2 * Y2r[r4][4];
        }
      }
    }
  }

  // ---- reduce over quads (butterfly), stash per-wave f-half, combine ----
  #pragma unroll
  for (int c = 0; c < 9; ++c)
    #pragma unroll
    for (int ftl = 0; ftl < 2; ++ftl) {
      float v = acc[c][ftl];
      v += __shfl_xor(v, 16);
      v += __shfl_xor(v, 32);
      acc[c][ftl] = v;
    }
  if (quad == 0) {
    #pragma unroll
    for (int c = 0; c < 9; ++c)
      #pragma unroll
      for (int ftl = 0; ftl < 2; ++ftl)
        red[wave][(fh * 2 + ftl) * 16 + lo][c] = acc[c][ftl];
  }
  __syncthreads();
  // waves {0,2} hold f<32 (stile parities 0/1), waves {1,3} hold f>=32
  for (int o = t; o < 576; o += 256) {
    int f = o / 9, c = o % 9;
    int b = (f >= 32) ? 1 : 0;
    ws[WS_A + (half * NN + j) * 576 + f * 9 + c] =
        red[b][f][c] + red[b + 2][f][c];  // partial (unscaled)
  }
}

// ---------------- node update (grid 512 x 64 thr) ----------------
template <int L>
__global__ __launch_bounds__(64) void k_node(
    const int* __restrict__ nodef, const void* __restrict__ W_lin,
    const void* __restrict__ Wp0, const void* __restrict__ Wp1,
    const void* __restrict__ Wr1, const void* __restrict__ br1,
    const void* __restrict__ Wr2g, float* __restrict__ ws,
    void* __restrict__ out) {
  int n = blockIdx.x, f = threadIdx.x;
  const int isf32 = ((const int*)ws)[WS_FLAG];
  const float* Ap0 = ws + WS_A + n * 576 + f * 9;
  const float* Ap1 = Ap0 + NN * 576;
  float a[9];
  #pragma unroll
  for (int c = 0; c < 9; ++c) a[c] = (Ap0[c] + Ap1[c]) * (1.f / 511.f);
  int sp = nodef[n] - 1;
  int b0i = ((L * 5 + sp) * 64 + f) * 6;
  int b1i = ((L * 5 + sp) * 64 + f) * 3;
  float A0 = a[0];
  float n1 = a[1] * a[1] + a[2] * a[2] + a[3] * a[3];
  float n2 = a[4] * a[4] + a[5] * a[5] + a[6] * a[6] + a[7] * a[7] + a[8] * a[8];
  float A02 = A0 * A0;
  float out0 = ld(Wp0, b0i + 0, isf32) * A0 + ld(Wp0, b0i + 1, isf32) * A02 +
               ld(Wp0, b0i + 2, isf32) * A02 * A0 + ld(Wp0, b0i + 3, isf32) * n1 +
               ld(Wp0, b0i + 4, isf32) * n2 + ld(Wp0, b0i + 5, isf32) * A0 * n1;
  float gp = ld(Wp1, b1i + 0, isf32) + ld(Wp1, b1i + 1, isf32) * A0 +
             ld(Wp1, b1i + 2, isf32) * A02;
  float o1x = gp * a[1], o1y = gp * a[2], o1z = gp * a[3];

  __shared__ float s0l[64];
  __shared__ float o1l[3][64];
  __shared__ float hl[64];
  s0l[f] = out0;
  if (L == 0) { o1l[0][f] = o1x; o1l[1][f] = o1y; o1l[2][f] = o1z; }
  __syncthreads();

  if (L == 0) {
    float b0 = 0.f, bx = 0.f, by = 0.f, bz = 0.f;
    #pragma unroll 8
    for (int q = 0; q < 64; ++q) {
      float w0 = ld(W_lin, 3 * 4096 + q * 64 + f, isf32);  // layer1, path0
      float w1 = ld(W_lin, 4 * 4096 + q * 64 + f, isf32);  // layer1, path1
      b0 += s0l[q] * w0;
      bx += o1l[0][q] * w1; by += o1l[1][q] * w1; bz += o1l[2][q] * w1;
    }
    f32x4 o = {b0, bx, by, bz};
    *(f32x4*)&ws[WS_XS1 + (n * 64 + f) * 4] = o;
  }

  float hacc = ld(br1, L * 64 + f, isf32);
  #pragma unroll 8
  for (int q = 0; q < 64; ++q)
    hacc += s0l[q] * ld(Wr1, (L * 64 + q) * 64 + f, isf32);
  float hr = hacc / (1.f + __expf(-hacc));
  hl[f] = hr;
  __syncthreads();
  float gacc = 0.f;
  #pragma unroll 8
  for (int m = 0; m < 64; ++m)
    gacc += hl[m] * ld(Wr2g, (L * 64 + m) * 64 + f, isf32);
  float px = gacc * o1x, py = gacc * o1y, pz = gacc * o1z;
  #pragma unroll
  for (int off = 32; off > 0; off >>= 1) {
    px += __shfl_down(px, off);
    py += __shfl_down(py, off);
    pz += __shfl_down(pz, off);
  }
  if (f == 0) {
    if (L == 0) {
      ws[WS_DELTA + n * 3 + 0] = px;
      ws[WS_DELTA + n * 3 + 1] = py;
      ws[WS_DELTA + n * 3 + 2] = pz;
      ws[WS_POS2 + n * 3 + 0] = ws[WS_POS + n * 3 + 0] + px;
      ws[WS_POS2 + n * 3 + 1] = ws[WS_POS + n * 3 + 1] + py;
      ws[WS_POS2 + n * 3 + 2] = ws[WS_POS + n * 3 + 2] + pz;
    } else {
      float ox = ws[WS_DELTA + n * 3 + 0] + px;
      float oy = ws[WS_DELTA + n * 3 + 1] + py;
      float oz = ws[WS_DELTA + n * 3 + 2] + pz;
      if (isf32) {
        float* o = (float*)out;
        o[n * 3 + 0] = ox; o[n * 3 + 1] = oy; o[n * 3 + 2] = oz;
      } else {
        bf16* o = (bf16*)out;
        o[n * 3 + 0] = __float2bfloat16(ox);
        o[n * 3 + 1] = __float2bfloat16(oy);
        o[n * 3 + 2] = __float2bfloat16(oz);
      }
    }
  }
}

extern "C" void kernel_launch(void* const* d_in, const int* in_sizes, int n_in,
                              void* d_out, int out_size, void* d_ws, size_t ws_size,
                              hipStream_t stream) {
  const void* positions = d_in[0];
  const int*  nodef     = (const int*)d_in[1];
  const void* te        = d_in[2];
  const void* W_embed   = d_in[5];
  const void* b_embed   = d_in[6];
  const void* W_lin     = d_in[7];
  const void* W_e1      = d_in[8];
  const void* b_e1      = d_in[9];
  const void* W_e2      = d_in[10];
  const void* Wp0       = d_in[11];
  const void* Wp1       = d_in[12];
  const void* Wr1       = d_in[13];
  const void* br1       = d_in[14];
  const void* Wr2g      = d_in[16];
  float* ws = (float*)d_ws;
  (void)in_sizes; (void)n_in; (void)out_size; (void)ws_size;

  k_pre<<<dim3(6), dim3(256), 0, stream>>>(positions, te, W_embed, b_embed,
                                           W_lin, ws);
  k_edge<0><<<dim3(1024), dim3(256), 0, stream>>>(nodef, W_e1, b_e1, W_e2, ws);
  k_node<0><<<dim3(512), dim3(64), 0, stream>>>(nodef, W_lin, Wp0, Wp1, Wr1,
                                                br1, Wr2g, ws, d_out);
  k_edge<1><<<dim3(1024), dim3(256), 0, stream>>>(nodef, W_e1, b_e1, W_e2, ws);
  k_node<1><<<dim3(512), dim3(64), 0, stream>>>(nodef, W_lin, Wp0, Wp1, Wr1,
                                                br1, Wr2g, ws, d_out);
}

// Round 20
// 187.120 us; speedup vs baseline: 1.1884x; 1.1884x over previous
//
#include <hip/hip_runtime.h>
#include <hip/hip_bf16.h>

using bf16 = __hip_bfloat16;
using bf16x8 = __attribute__((ext_vector_type(8))) short;  // 8 bf16 (4 VGPRs)
using f32x4  = __attribute__((ext_vector_type(4))) float;

#define NN 512
#define NS 511

// ---------------- workspace layout (float offsets) ----------------
enum : int {
  WS_FLAG = 0,        // int: 0 = bf16 inputs, 1 = f32 inputs
  WS_X0S  = 16,       // [5][64] species-indexed layer-0 x0 rows (only 5 distinct!)
  WS_POS  = 336,      // [512][3] positions fp32 (layer 0)
  WS_POS2 = 1872,     // [512][3] positions after layer-0 update (layer 1 reads)
  WS_DELTA= 3408,     // [512][3] layer-0 displacement
  WS_XS1  = 4960,     // [512][64][4] (x0,x1x,x1y,x1z) for layer 1 — 16B aligned
};                     // end = 136032 floats ~= 544 KB

// exact RNE float->bf16 bits (no NaN inputs here)
__device__ __forceinline__ short f2b(float x) {
  unsigned u = __builtin_bit_cast(unsigned, x);
  unsigned r = (u + 0x7fffu + ((u >> 16) & 1u)) >> 16;
  return (short)r;
}

// dtype-branched scalar load (branch, NOT select: f32-view OOB if input is bf16)
__device__ __forceinline__ float ld(const void* p, int i, int isf32) {
  if (isf32) return ((const float*)p)[i];
  return __bfloat162float(((const bf16*)p)[i]);
}

// ---------------- pre (6 blocks): detect + pos convert + X0S ----------------
// Blocks 0-4 compute X0S[sp] (reduction split across thread chunks, global
// loads lane-coalesced); block 5 converts positions + publishes dtype flag.
__global__ __launch_bounds__(256) void k_pre(
    const void* __restrict__ positions, const void* __restrict__ te,
    const void* __restrict__ W_embed, const void* __restrict__ b_embed,
    const void* __restrict__ W_lin, float* __restrict__ ws) {
  const int b = blockIdx.x, t = threadIdx.x;
  __shared__ int flag_s;
  __shared__ float tvp[4][64];
  __shared__ float hst[64];
  __shared__ float xp[4][64];
  if (t < 64) {
    int cnt = 0;
    #pragma unroll
    for (int kq = 0; kq < 4; ++kq) {
      float v = __bfloat162float(((const bf16*)W_embed)[t + kq * 64]);
      float av = fabsf(v);
      cnt += (v == v && av > 1e-8f && av < 1e4f) ? 1 : 0;
    }
    #pragma unroll
    for (int off = 32; off > 0; off >>= 1) cnt += __shfl_down(cnt, off);
    if (t == 0) flag_s = (cnt >= 240) ? 0 : 1;
  }
  __syncthreads();
  const int isf32 = flag_s;

  if (b == 5) {
    if (t == 0) ((int*)ws)[WS_FLAG] = isf32;
    for (int idx = t; idx < NN * 3; idx += 256)
      ws[WS_POS + idx] = ld(positions, idx, isf32);
    return;
  }
  {
    int q = t & 63, kc = t >> 6;  // 4 k-chunks of 8
    float ptv = 0.f;
    #pragma unroll
    for (int k = kc * 8; k < kc * 8 + 8; ++k)
      ptv += ld(te, k, isf32) * ld(W_embed, (5 + k) * 64 + q, isf32);
    tvp[kc][q] = ptv;
  }
  __syncthreads();
  if (t < 64)
    hst[t] = tvp[0][t] + tvp[1][t] + tvp[2][t] + tvp[3][t] +
             ld(b_embed, t, isf32) + ld(W_embed, b * 64 + t, isf32);
  __syncthreads();
  {
    int f = t & 63, qc = t >> 6;  // 4 q-chunks of 16
    float px = 0.f;
    #pragma unroll
    for (int q2 = qc * 16; q2 < qc * 16 + 16; ++q2)
      px += hst[q2] * ld(W_lin, q2 * 64 + f, isf32);  // layer0 path0
    xp[qc][f] = px;
  }
  __syncthreads();
  if (t < 64)
    ws[WS_X0S + b * 64 + t] = xp[0][t] + xp[1][t] + xp[2][t] + xp[3][t];
}

// ---------------- fused edge + aggregate + node update (proven optimum) --------------
// One block per receiver j (grid 512); 256 threads (4 waves). CAPLESS
// __launch_bounds__: a min-waves bound splits the unified VGPR/AGPR budget
// 50/50 and forces ~1KB/thread HBM-speed scratch spill (r4-r8, r11).
// SESSION CEILING NOTE: residency is pinned at 2 waves/SIMD by the unified
// VGPR+AGPR allocation (AGPR side ~96+ regs, invisible in VGPR_Count and
// untouchable from HIP source) — hoisting (r5/r6/r12), dieting (r11/r13),
// ft-split (r15), factorized L0 (r16/r17), split-grid (r19) all regressed.
// 62-63 us/dispatch is the measured floor of this body at that residency.
template <int L>
__global__ __launch_bounds__(256) void k_edgenode(
    const int* __restrict__ nodef, const void* __restrict__ W_lin,
    const void* __restrict__ W_e1, const void* __restrict__ b_e1,
    const void* __restrict__ W_e2, const void* __restrict__ Wp0,
    const void* __restrict__ Wp1, const void* __restrict__ Wr1,
    const void* __restrict__ br1, const void* __restrict__ Wr2g,
    float* __restrict__ ws, void* __restrict__ out) {
  constexpr int HAS1 = L;          // s1==0 in layer 0
  constexpr int K = HAS1 ? 5 : 3;  // s2==0 always
  constexpr int N = K * 64;
  const int j = blockIdx.x;
  const int t = threadIdx.x;
  const int lane = t & 63;
  const int wave = t >> 6;          // 0..3
  const int quad = lane >> 4;
  const int lo = lane & 15;

  __shared__ short Bhi[N * 40];     // [n][h], row stride 40 shorts (80B, 16B-aligned)
  __shared__ float red[4][64][9];
  __shared__ float Af[64][9];
  __shared__ float s0l[64];
  __shared__ float o1l[3][64];
  __shared__ float hl[64];
  __shared__ float X0l[320];        // L0: species-indexed x0 table

  const int isf32 = ((const int*)ws)[WS_FLAG];

  {  // stage W2 slice -> LDS bf16 (direct bit copy if input already bf16)
    for (int idx = t; idx < N * 32; idx += 256) {
      int n = idx >> 5, h = idx & 31;
      int kp = n >> 6, f = n & 63;
      int src = (L * 32 + h) * 384 + f * 6 + kp;
      short bits;
      if (isf32) bits = f2b(((const float*)W_e2)[src]);
      else       bits = ((const short*)W_e2)[src];
      Bhi[n * 40 + h] = bits;
    }
    if (!HAS1) {
      for (int idx = t; idx < 320; idx += 256) X0l[idx] = ws[WS_X0S + idx];
    }
  }
  const float* pos = ws + (L ? WS_POS2 : WS_POS);
  const f32x4* xs = (const f32x4*)(ws + WS_XS1);  // used only for L==1
  float we1v[8], be1v[8];
  #pragma unroll
  for (int i = 0; i < 8; ++i) {
    we1v[i] = ld(W_e1, L * 32 + quad * 8 + i, isf32);
    be1v[i] = ld(b_e1, L * 32 + quad * 8 + i, isf32);
  }
  const float pjx = pos[j * 3 + 0], pjy = pos[j * 3 + 1], pjz = pos[j * 3 + 2];

  const float s3 = 1.7320508075688772f;
  const float s5h = 1.118033988749895f;    // 0.5*sqrt(5)
  const float s15 = 3.872983346207417f;
  const float s15h = 1.9364916731037085f;  // 0.5*sqrt(15)

  float acc[9][4] = {};  // [c][ft]
  __syncthreads();

  #pragma unroll 1
  for (int stile = wave; stile < 32; stile += 4) {
    // ---- A fragment: he for sender m=lo, k=quad*8+i ----
    bf16x8 af;
    {
      int ida = stile * 16 + lo;
      int ia = ida + (ida >= j);
      if (ia > 511) ia = 511;
      float pix = pos[ia * 3 + 0], piy = pos[ia * 3 + 1], piz = pos[ia * 3 + 2];
      float vx = pjx - pix, vy = pjy - piy, vz = pjz - piz;
      float r = sqrtf(vx * vx + vy * vy + vz * vz);
      #pragma unroll
      for (int i = 0; i < 8; ++i) {
        float x = r * we1v[i] + be1v[i];
        float he = x / (1.f + __expf(-x));
        af[i] = f2b(he);
      }
    }
    // ---- Y + indices (+ species for L0) for this quad's 4 row-senders ----
    float Y1r[4][3], Y2r[4][5];
    int ir[4], sp4[4];
    bool vld[4];
    #pragma unroll
    for (int r4 = 0; r4 < 4; ++r4) {
      int idx = stile * 16 + quad * 4 + r4;
      vld[r4] = idx < NS;
      int i = idx + (idx >= j);
      if (i > 511) i = 511;
      ir[r4] = i;
      if (!HAS1) sp4[r4] = nodef[i] - 1;
      float pix = pos[i * 3 + 0], piy = pos[i * 3 + 1], piz = pos[i * 3 + 2];
      float vx = pjx - pix, vy = pjy - piy, vz = pjz - piz;
      float r2 = vx * vx + vy * vy + vz * vz;
      float rinv = r2 > 0.f ? rsqrtf(r2) : 0.f;
      float ux = vx * rinv, uy = vy * rinv, uz = vz * rinv;
      Y1r[r4][0] = s3 * ux; Y1r[r4][1] = s3 * uy; Y1r[r4][2] = s3 * uz;
      Y2r[r4][0] = s15 * ux * uy;
      Y2r[r4][1] = s15 * uy * uz;
      Y2r[r4][2] = s5h * (3.f * uz * uz - 1.f);
      Y2r[r4][3] = s15 * ux * uz;
      Y2r[r4][4] = s15h * (ux * ux - uy * uy);
    }
    // ---- per f-subtile: loads, K MFMAs, then message math ----
    #pragma unroll
    for (int ft = 0; ft < 4; ++ft) {
      int fcol = ft * 16 + lo;
      f32x4 xv[4];
      if (HAS1) {
        #pragma unroll
        for (int r4 = 0; r4 < 4; ++r4) xv[r4] = xs[ir[r4] * 64 + fcol];
      } else {
        #pragma unroll
        for (int r4 = 0; r4 < 4; ++r4) {
          f32x4 v = {X0l[sp4[r4] * 64 + fcol], 0.f, 0.f, 0.f};
          xv[r4] = v;
        }
      }
      f32x4 C[K];
      #pragma unroll
      for (int kp = 0; kp < K; ++kp) {
        const bf16x8 bh = *(const bf16x8*)&Bhi[(kp * 64 + fcol) * 40 + quad * 8];
        f32x4 c = {0.f, 0.f, 0.f, 0.f};
        C[kp] = __builtin_amdgcn_mfma_f32_16x16x32_bf16(af, bh, c, 0, 0, 0);
      }
      #pragma unroll
      for (int r4 = 0; r4 < 4; ++r4) {
        if (vld[r4]) {
          float s0 = xv[r4].x;
          float w0 = C[0][r4], w1 = C[1][r4], w2 = C[2][r4];
          if (HAS1) {
            float s1x = xv[r4].y, s1y = xv[r4].z, s1z = xv[r4].w;
            float w3 = C[3][r4], w4 = C[4][r4];
            float d1 = s1x * Y1r[r4][0] + s1y * Y1r[r4][1] + s1z * Y1r[r4][2];
            float cx = s1y * Y1r[r4][2] - s1z * Y1r[r4][1];
            float cy = s1z * Y1r[r4][0] - s1x * Y1r[r4][2];
            float cz = s1x * Y1r[r4][1] - s1y * Y1r[r4][0];
            acc[0][ft] += w0 * s0 + w3 * d1;
            float t1 = w1 * s0;
            acc[1][ft] += t1 * Y1r[r4][0] + w4 * cx;
            acc[2][ft] += t1 * Y1r[r4][1] + w4 * cy;
            acc[3][ft] += t1 * Y1r[r4][2] + w4 * cz;
          } else {
            acc[0][ft] += w0 * s0;
            float t1 = w1 * s0;
            acc[1][ft] += t1 * Y1r[r4][0];
            acc[2][ft] += t1 * Y1r[r4][1];
            acc[3][ft] += t1 * Y1r[r4][2];
          }
          float t2 = w2 * s0;
          acc[4][ft] += t2 * Y2r[r4][0];
          acc[5][ft] += t2 * Y2r[r4][1];
          acc[6][ft] += t2 * Y2r[r4][2];
          acc[7][ft] += t2 * Y2r[r4][3];
          acc[8][ft] += t2 * Y2r[r4][4];
        }
      }
    }
  }

  // ---- reduce over quads (butterfly), then over 4 waves (LDS) -> Af ----
  #pragma unroll
  for (int c = 0; c < 9; ++c)
    #pragma unroll
    for (int ft = 0; ft < 4; ++ft) {
      float v = acc[c][ft];
      v += __shfl_xor(v, 16);
      v += __shfl_xor(v, 32);
      acc[c][ft] = v;
    }
  if (quad == 0) {
    #pragma unroll
    for (int c = 0; c < 9; ++c)
      #pragma unroll
      for (int ft = 0; ft < 4; ++ft)
        red[wave][ft * 16 + lo][c] = acc[c][ft];
  }
  __syncthreads();
  for (int o = t; o < 576; o += 256) {
    int f = o / 9, c = o % 9;
    Af[f][c] = (red[0][f][c] + red[1][f][c] + red[2][f][c] + red[3][f][c]) *
               (1.f / 511.f);
  }
  __syncthreads();

  // ---- node-update tail (wave 0; other waves ride the barriers) ----
  float out0 = 0.f, o1x = 0.f, o1y = 0.f, o1z = 0.f;
  if (t < 64) {
    int f = t;
    float a[9];
    #pragma unroll
    for (int c = 0; c < 9; ++c) a[c] = Af[f][c];
    int sp = nodef[j] - 1;
    int b0i = ((L * 5 + sp) * 64 + f) * 6;
    int b1i = ((L * 5 + sp) * 64 + f) * 3;
    float A0 = a[0];
    float n1 = a[1] * a[1] + a[2] * a[2] + a[3] * a[3];
    float n2 = a[4] * a[4] + a[5] * a[5] + a[6] * a[6] + a[7] * a[7] + a[8] * a[8];
    float A02 = A0 * A0;
    out0 = ld(Wp0, b0i + 0, isf32) * A0 + ld(Wp0, b0i + 1, isf32) * A02 +
           ld(Wp0, b0i + 2, isf32) * A02 * A0 + ld(Wp0, b0i + 3, isf32) * n1 +
           ld(Wp0, b0i + 4, isf32) * n2 + ld(Wp0, b0i + 5, isf32) * A0 * n1;
    float gp = ld(Wp1, b1i + 0, isf32) + ld(Wp1, b1i + 1, isf32) * A0 +
               ld(Wp1, b1i + 2, isf32) * A02;
    o1x = gp * a[1]; o1y = gp * a[2]; o1z = gp * a[3];
    s0l[f] = out0;
    if (L == 0) { o1l[0][f] = o1x; o1l[1][f] = o1y; o1l[2][f] = o1z; }
  }
  __syncthreads();
  if (t < 64) {
    int f = t;
    if (L == 0) {
      // next-layer node linear into XS1 (read in the next dispatch)
      float b0 = 0.f, bx = 0.f, by = 0.f, bz = 0.f;
      #pragma unroll 8
      for (int q = 0; q < 64; ++q) {
        float w0 = ld(W_lin, 3 * 4096 + q * 64 + f, isf32);  // layer1, path0
        float w1 = ld(W_lin, 4 * 4096 + q * 64 + f, isf32);  // layer1, path1
        b0 += s0l[q] * w0;
        bx += o1l[0][q] * w1; by += o1l[1][q] * w1; bz += o1l[2][q] * w1;
      }
      f32x4 o = {b0, bx, by, bz};
      *(f32x4*)&ws[WS_XS1 + (j * 64 + f) * 4] = o;
    }
    float hacc = ld(br1, L * 64 + f, isf32);
    #pragma unroll 8
    for (int q = 0; q < 64; ++q)
      hacc += s0l[q] * ld(Wr1, (L * 64 + q) * 64 + f, isf32);
    hl[f] = hacc / (1.f + __expf(-hacc));
  }
  __syncthreads();
  if (t < 64) {
    int f = t;
    float gacc = 0.f;
    #pragma unroll 8
    for (int m = 0; m < 64; ++m)
      gacc += hl[m] * ld(Wr2g, (L * 64 + m) * 64 + f, isf32);
    float px = gacc * o1x, py = gacc * o1y, pz = gacc * o1z;
    #pragma unroll
    for (int off = 32; off > 0; off >>= 1) {
      px += __shfl_down(px, off);
      py += __shfl_down(py, off);
      pz += __shfl_down(pz, off);
    }
    if (f == 0) {
      if (L == 0) {
        ws[WS_DELTA + j * 3 + 0] = px;
        ws[WS_DELTA + j * 3 + 1] = py;
        ws[WS_DELTA + j * 3 + 2] = pz;
        ws[WS_POS2 + j * 3 + 0] = pos[j * 3 + 0] + px;
        ws[WS_POS2 + j * 3 + 1] = pos[j * 3 + 1] + py;
        ws[WS_POS2 + j * 3 + 2] = pos[j * 3 + 2] + pz;
      } else {
        float ox = ws[WS_DELTA + j * 3 + 0] + px;
        float oy = ws[WS_DELTA + j * 3 + 1] + py;
        float oz = ws[WS_DELTA + j * 3 + 2] + pz;
        if (isf32) {
          float* o = (float*)out;
          o[j * 3 + 0] = ox; o[j * 3 + 1] = oy; o[j * 3 + 2] = oz;
        } else {
          bf16* o = (bf16*)out;
          o[j * 3 + 0] = __float2bfloat16(ox);
          o[j * 3 + 1] = __float2bfloat16(oy);
          o[j * 3 + 2] = __float2bfloat16(oz);
        }
      }
    }
  }
}

extern "C" void kernel_launch(void* const* d_in, const int* in_sizes, int n_in,
                              void* d_out, int out_size, void* d_ws, size_t ws_size,
                              hipStream_t stream) {
  const void* positions = d_in[0];
  const int*  nodef     = (const int*)d_in[1];
  const void* te        = d_in[2];
  const void* W_embed   = d_in[5];
  const void* b_embed   = d_in[6];
  const void* W_lin     = d_in[7];
  const void* W_e1      = d_in[8];
  const void* b_e1      = d_in[9];
  const void* W_e2      = d_in[10];
  const void* Wp0       = d_in[11];
  const void* Wp1       = d_in[12];
  const void* Wr1       = d_in[13];
  const void* br1       = d_in[14];
  const void* Wr2g      = d_in[16];
  float* ws = (float*)d_ws;
  (void)in_sizes; (void)n_in; (void)out_size; (void)ws_size;

  k_pre<<<dim3(6), dim3(256), 0, stream>>>(positions, te, W_embed, b_embed,
                                           W_lin, ws);
  k_edgenode<0><<<dim3(512), dim3(256), 0, stream>>>(
      nodef, W_lin, W_e1, b_e1, W_e2, Wp0, Wp1, Wr1, br1, Wr2g, ws, d_out);
  k_edgenode<1><<<dim3(512), dim3(256), 0, stream>>>(
      nodef, W_lin, W_e1, b_e1, W_e2, Wp0, Wp1, Wr1, br1, Wr2g, ws, d_out);
}